// Round 8
// baseline (270.016 us; speedup 1.0000x reference)
//
#include <hip/hip_runtime.h>

constexpr int NN  = 50000;
constexpr int NE  = 1600000;
constexpr int CIN = 384;
constexpr int CH  = 128;
constexpr int CO  = 64;

constexpr int NB = (NN + 255) / 256;              // 196 dst-buckets of 256 nodes
constexpr int BUCKET_CAP = 16384;                 // append region per bucket (mean 8163)
constexpr int SCAT_EPB     = 4096;                // 256 thr * 16 edges
constexpr int SCAT_BLOCKS  = (NE + SCAT_EPB - 1) / SCAT_EPB;     // 391
constexpr int G1_TILES     = (NN + 127) / 128;    // 391 blocks of 128 rows
constexpr int G2_TILES     = (NN + 127) / 128;    // 391

typedef __attribute__((ext_vector_type(8))) short short8;
typedef __attribute__((ext_vector_type(4))) float f32x4;

// ---------------- bf16 helpers ----------------

__device__ inline unsigned short f2bf(float f) {
    union { float f; unsigned int u; } v; v.f = f;
    unsigned int u = v.u + 0x7FFFu + ((v.u >> 16) & 1u);   // round-to-nearest-even
    return (unsigned short)(u >> 16);
}
__device__ inline float bf2f(unsigned short h) { return __uint_as_float((unsigned int)h << 16); }
__device__ inline float bflo(unsigned int u) { return __uint_as_float(u << 16); }
__device__ inline float bfhi(unsigned int u) { return __uint_as_float(u & 0xFFFF0000u); }

// convert 8 fp32 -> hi/lo bf16 short8
__device__ inline void cvt8(const float* f, short8& vh, short8& vl) {
    #pragma unroll
    for (int i = 0; i < 8; ++i) {
        unsigned short h = f2bf(f[i]);
        vh[i] = (short)h;
        vl[i] = (short)f2bf(f[i] - bf2f(h));
    }
}

// ---------------- W transpose + hi/lo bf16 split + cursor init ----------------

__global__ __launch_bounds__(256) void wprep(const float* __restrict__ W1, const float* __restrict__ W2,
                                             unsigned short* __restrict__ W1t_hi, unsigned short* __restrict__ W1t_lo,
                                             unsigned short* __restrict__ W2t_hi, unsigned short* __restrict__ W2t_lo,
                                             int* __restrict__ bucket_cursor) {
    int i = blockIdx.x * 256 + threadIdx.x;
    if (blockIdx.x == 0 && threadIdx.x < NB)
        bucket_cursor[threadIdx.x] = threadIdx.x * BUCKET_CAP;
    if (i < CIN * CH) {
        int k = i / CH, c = i % CH;
        float v = W1[i];
        unsigned short h = f2bf(v);
        W1t_hi[c * CIN + k] = h;
        W1t_lo[c * CIN + k] = f2bf(v - bf2f(h));
    } else if (i < CIN * CH + CH * CO) {
        int j = i - CIN * CH;
        int k = j / CO, c = j % CO;
        float v = W2[j];
        unsigned short h = f2bf(v);
        W2t_hi[c * CH + k] = h;
        W2t_lo[c * CH + k] = f2bf(v - bf2f(h));
    }
}

// ---------------- fused MFMA-GEMM1 (LDS-free) + bucketed edge scatter ----------------
// blocks [0, SCAT_BLOCKS): bin edges into per-bucket append regions (uses LDS hist).
// blocks [SCAT_BLOCKS, +G1_TILES): h1 = x @ W1, bf16 hi/lo MFMA, NO LDS/barriers:
//   A rows are wave-private (per-lane 32B fp32 loads, reg convert); B fragments
//   are per-lane 16B loads from the L1-resident pre-transposed W tables.

__global__ __launch_bounds__(256, 4) void fused_gemm1_scatter(const int* __restrict__ src,
                                                              const int* __restrict__ dst,
                                                              int* __restrict__ bucket_cursor,
                                                              unsigned int* __restrict__ pairs,
                                                              const float* __restrict__ X,
                                                              const unsigned short* __restrict__ Wt_hi,
                                                              const unsigned short* __restrict__ Wt_lo,
                                                              unsigned short* __restrict__ Hb) {
    __shared__ int hist[NB];
    __shared__ int base_s[NB];

    int tid = threadIdx.x;
    if (blockIdx.x < SCAT_BLOCKS) {
        int e0 = blockIdx.x * SCAT_EPB;
        for (int i = tid; i < NB; i += 256) hist[i] = 0;
        __syncthreads();
        int key[16];
        unsigned int pay[16];
        #pragma unroll
        for (int k = 0; k < 16; ++k) {
            int e = e0 + k * 256 + tid;
            if (e < NE) {
                int s = src[e], d = dst[e];
                int b = d >> 8;
                int pos = atomicAdd(&hist[b], 1);
                key[k] = b | (pos << 8);
                pay[k] = (unsigned int)s | ((unsigned int)(d & 255) << 16);
            } else {
                key[k] = -1;
            }
        }
        __syncthreads();
        for (int i = tid; i < NB; i += 256)
            base_s[i] = hist[i] ? atomicAdd(&bucket_cursor[i], hist[i]) : 0;
        __syncthreads();
        #pragma unroll
        for (int k = 0; k < 16; ++k) {
            if (key[k] >= 0) {
                int b = key[k] & 255, pos = key[k] >> 8;
                pairs[base_s[b] + pos] = pay[k];
            }
        }
        return;
    }

    // ---- GEMM1: 128 rows x 128 cols per block, 4 waves x (32r x 128c) ----
    int wid = tid >> 6, lane = tid & 63;
    int row0 = (blockIdx.x - SCAT_BLOCKS) * 128;
    int r = lane & 15, ko = (lane >> 4) * 8;
    f32x4 acc[2][8] = {};

    int grow0 = row0 + wid * 32 + r;          // rt=0 row
    int grow1 = grow0 + 16;                   // rt=1 row
    const float* xp0 = X + (size_t)grow0 * CIN + ko;
    const float* xp1 = X + (size_t)grow1 * CIN + ko;
    bool ok0 = grow0 < NN, ok1 = grow1 < NN;

    for (int k0 = 0; k0 < CIN; k0 += 32) {
        short8 a_hi[2], a_lo[2];
        {
            float f[8];
            if (ok0) {
                const float4* p = reinterpret_cast<const float4*>(xp0 + k0);
                float4 v0 = p[0], v1 = p[1];
                f[0]=v0.x; f[1]=v0.y; f[2]=v0.z; f[3]=v0.w;
                f[4]=v1.x; f[5]=v1.y; f[6]=v1.z; f[7]=v1.w;
            } else {
                #pragma unroll
                for (int i = 0; i < 8; ++i) f[i] = 0.f;
            }
            cvt8(f, a_hi[0], a_lo[0]);
            if (ok1) {
                const float4* p = reinterpret_cast<const float4*>(xp1 + k0);
                float4 v0 = p[0], v1 = p[1];
                f[0]=v0.x; f[1]=v0.y; f[2]=v0.z; f[3]=v0.w;
                f[4]=v1.x; f[5]=v1.y; f[6]=v1.z; f[7]=v1.w;
            } else {
                #pragma unroll
                for (int i = 0; i < 8; ++i) f[i] = 0.f;
            }
            cvt8(f, a_hi[1], a_lo[1]);
        }
        const unsigned short* wh = Wt_hi + (size_t)r * CIN + k0 + ko;
        const unsigned short* wl = Wt_lo + (size_t)r * CIN + k0 + ko;
        #pragma unroll 4
        for (int ct = 0; ct < 8; ++ct) {
            short8 b_hi = *reinterpret_cast<const short8*>(wh + (size_t)ct * 16 * CIN);
            short8 b_lo = *reinterpret_cast<const short8*>(wl + (size_t)ct * 16 * CIN);
            #pragma unroll
            for (int rt = 0; rt < 2; ++rt) {
                acc[rt][ct] = __builtin_amdgcn_mfma_f32_16x16x32_bf16(a_hi[rt], b_hi, acc[rt][ct], 0, 0, 0);
                acc[rt][ct] = __builtin_amdgcn_mfma_f32_16x16x32_bf16(a_hi[rt], b_lo, acc[rt][ct], 0, 0, 0);
                acc[rt][ct] = __builtin_amdgcn_mfma_f32_16x16x32_bf16(a_lo[rt], b_hi, acc[rt][ct], 0, 0, 0);
            }
        }
    }
    // epilogue: D row=(lane>>4)*4+j, col=lane&15 per 16x16 tile
    int cl = lane & 15, rg = lane >> 4;
    #pragma unroll
    for (int rt = 0; rt < 2; ++rt) {
        #pragma unroll
        for (int j = 0; j < 4; ++j) {
            int row = row0 + wid * 32 + rt * 16 + rg * 4 + j;
            if (row < NN) {
                unsigned short* hp = Hb + (size_t)row * CH + cl;
                #pragma unroll
                for (int ct = 0; ct < 8; ++ct)
                    hp[ct * 16] = f2bf(acc[rt][ct][j]);
            }
        }
    }
}

// ---------------- bucket totals -> exclusive scan ----------------

__global__ __launch_bounds__(256) void bucket_scan(const int* __restrict__ bucket_cursor,
                                                   int* __restrict__ bucket_start) {
    __shared__ int tmp[256];
    int t = threadIdx.x;
    int v = (t < NB) ? (bucket_cursor[t] - t * BUCKET_CAP) : 0;
    tmp[t] = v;
    __syncthreads();
    for (int off = 1; off < 256; off <<= 1) {
        int add = (t >= off) ? tmp[t - off] : 0;
        __syncthreads();
        tmp[t] += add;
        __syncthreads();
    }
    if (t < NB) bucket_start[t] = tmp[t] - v;
    if (t == NB - 1) bucket_start[NB] = tmp[t];   // == NE
}

// ---------------- in-bucket count + sort -> CSR, row_start, dinv ----------------

__global__ __launch_bounds__(1024) void bucket_sort(const unsigned int* __restrict__ pairs,
                                                    const int* __restrict__ bucket_cursor,
                                                    const int* __restrict__ bucket_start,
                                                    int* __restrict__ row_start,
                                                    float* __restrict__ dinv,
                                                    unsigned short* __restrict__ csr_src) {
    __shared__ int cnt[256];
    __shared__ int pref[256];
    __shared__ int cur[256];
    int b = blockIdx.x, t = threadIdx.x;
    int p0 = b * BUCKET_CAP;
    int ne = bucket_cursor[b] - p0;
    int out0 = bucket_start[b];
    if (t < 256) cnt[t] = 0;
    __syncthreads();
    for (int i = t; i < ne; i += 1024)
        atomicAdd(&cnt[(pairs[p0 + i] >> 16) & 255], 1);
    __syncthreads();
    if (t < 256) pref[t] = cnt[t];
    __syncthreads();
    for (int off = 1; off < 256; off <<= 1) {
        int add = (t < 256 && t >= off) ? pref[t - off] : 0;
        __syncthreads();
        if (t < 256) pref[t] += add;
        __syncthreads();
    }
    if (t < 256) {
        int n = (b << 8) + t;
        if (n < NN) {
            int rs = out0 + pref[t] - cnt[t];
            row_start[n] = rs;
            cur[t] = rs;
            dinv[n] = rsqrtf((float)(cnt[t] + 1));  // + self-loop
        }
    }
    if (b == NB - 1 && t == 0) row_start[NN] = NE;
    __syncthreads();
    for (int i = t; i < ne; i += 1024) {
        unsigned int p = pairs[p0 + i];
        int pos = atomicAdd(&cur[(p >> 16) & 255], 1);
        csr_src[pos] = (unsigned short)(p & 0xFFFF);
    }
}

// ---------------- MFMA GEMM2 (LDS-free): h2 = g1 @ W2, bf16 out ----------------

__global__ __launch_bounds__(256, 4) void gemm2_kernel(const float* __restrict__ X,
                                                       const unsigned short* __restrict__ Wt_hi,
                                                       const unsigned short* __restrict__ Wt_lo,
                                                       unsigned short* __restrict__ Hb) {
    int tid = threadIdx.x;
    int wid = tid >> 6, lane = tid & 63;
    int row0 = blockIdx.x * 128;
    int r = lane & 15, ko = (lane >> 4) * 8;
    f32x4 acc[2][4] = {};

    int grow0 = row0 + wid * 32 + r;
    int grow1 = grow0 + 16;
    const float* xp0 = X + (size_t)grow0 * CH + ko;
    const float* xp1 = X + (size_t)grow1 * CH + ko;
    bool ok0 = grow0 < NN, ok1 = grow1 < NN;

    for (int k0 = 0; k0 < CH; k0 += 32) {
        short8 a_hi[2], a_lo[2];
        {
            float f[8];
            if (ok0) {
                const float4* p = reinterpret_cast<const float4*>(xp0 + k0);
                float4 v0 = p[0], v1 = p[1];
                f[0]=v0.x; f[1]=v0.y; f[2]=v0.z; f[3]=v0.w;
                f[4]=v1.x; f[5]=v1.y; f[6]=v1.z; f[7]=v1.w;
            } else {
                #pragma unroll
                for (int i = 0; i < 8; ++i) f[i] = 0.f;
            }
            cvt8(f, a_hi[0], a_lo[0]);
            if (ok1) {
                const float4* p = reinterpret_cast<const float4*>(xp1 + k0);
                float4 v0 = p[0], v1 = p[1];
                f[0]=v0.x; f[1]=v0.y; f[2]=v0.z; f[3]=v0.w;
                f[4]=v1.x; f[5]=v1.y; f[6]=v1.z; f[7]=v1.w;
            } else {
                #pragma unroll
                for (int i = 0; i < 8; ++i) f[i] = 0.f;
            }
            cvt8(f, a_hi[1], a_lo[1]);
        }
        const unsigned short* wh = Wt_hi + (size_t)r * CH + k0 + ko;
        const unsigned short* wl = Wt_lo + (size_t)r * CH + k0 + ko;
        #pragma unroll
        for (int ct = 0; ct < 4; ++ct) {
            short8 b_hi = *reinterpret_cast<const short8*>(wh + (size_t)ct * 16 * CH);
            short8 b_lo = *reinterpret_cast<const short8*>(wl + (size_t)ct * 16 * CH);
            #pragma unroll
            for (int rt = 0; rt < 2; ++rt) {
                acc[rt][ct] = __builtin_amdgcn_mfma_f32_16x16x32_bf16(a_hi[rt], b_hi, acc[rt][ct], 0, 0, 0);
                acc[rt][ct] = __builtin_amdgcn_mfma_f32_16x16x32_bf16(a_hi[rt], b_lo, acc[rt][ct], 0, 0, 0);
                acc[rt][ct] = __builtin_amdgcn_mfma_f32_16x16x32_bf16(a_lo[rt], b_hi, acc[rt][ct], 0, 0, 0);
            }
        }
    }
    int cl = lane & 15, rg = lane >> 4;
    #pragma unroll
    for (int rt = 0; rt < 2; ++rt) {
        #pragma unroll
        for (int j = 0; j < 4; ++j) {
            int row = row0 + wid * 32 + rt * 16 + rg * 4 + j;
            if (row < NN) {
                unsigned short* hp = Hb + (size_t)row * CO + cl;
                #pragma unroll
                for (int ct = 0; ct < 4; ++ct)
                    hp[ct * 16] = f2bf(acc[rt][ct][j]);
            }
        }
    }
}

// ---------------- CSR gather-aggregation (bf16, 1 wave/node, 4 edges in flight) ----------------

__global__ __launch_bounds__(64) void agg1_kernel(const unsigned int* __restrict__ H,   // bf16x2, ld=64
                                                  const int* __restrict__ row_start,
                                                  const unsigned short* __restrict__ csr_src,
                                                  const float* __restrict__ dinv,
                                                  const float* __restrict__ bias,
                                                  float* __restrict__ OUT) {
    int n = blockIdx.x;
    int l = threadIdx.x;                // lane = channel pair {2l, 2l+1}
    float dn = dinv[n];
    unsigned int us = H[n * 64 + l];
    float a0 = dn * bflo(us), a1 = dn * bfhi(us);   // self-loop
    float b0 = 0.f, b1 = 0.f, c0 = 0.f, c1 = 0.f, d0 = 0.f, d1 = 0.f;
    int e0 = row_start[n], e1 = row_start[n + 1];
    for (int base = e0; base < e1; base += 64) {
        int m = min(64, e1 - base);
        int sv = csr_src[base + min(l, m - 1)];
        float wv = (l < m) ? dinv[sv] : 0.f;
        int j = 0;
        for (; j + 4 <= m; j += 4) {    // 4 independent row-gathers in flight
            int s0 = __shfl(sv, j),     s1 = __shfl(sv, j + 1);
            int s2 = __shfl(sv, j + 2), s3 = __shfl(sv, j + 3);
            float w0 = __shfl(wv, j),     w1 = __shfl(wv, j + 1);
            float w2 = __shfl(wv, j + 2), w3 = __shfl(wv, j + 3);
            unsigned int u0 = H[s0 * 64 + l];
            unsigned int u1 = H[s1 * 64 + l];
            unsigned int u2 = H[s2 * 64 + l];
            unsigned int u3 = H[s3 * 64 + l];
            a0 = fmaf(w0, bflo(u0), a0); a1 = fmaf(w0, bfhi(u0), a1);
            b0 = fmaf(w1, bflo(u1), b0); b1 = fmaf(w1, bfhi(u1), b1);
            c0 = fmaf(w2, bflo(u2), c0); c1 = fmaf(w2, bfhi(u2), c1);
            d0 = fmaf(w3, bflo(u3), d0); d1 = fmaf(w3, bfhi(u3), d1);
        }
        for (; j < m; ++j) {
            int s0 = __shfl(sv, j);
            float w0 = __shfl(wv, j);
            unsigned int u0 = H[s0 * 64 + l];
            a0 = fmaf(w0, bflo(u0), a0); a1 = fmaf(w0, bfhi(u0), a1);
        }
    }
    float o0 = fmaf(dn, (a0 + b0) + (c0 + d0), reinterpret_cast<const float2*>(bias)[l].x);
    float o1 = fmaf(dn, (a1 + b1) + (c1 + d1), reinterpret_cast<const float2*>(bias)[l].y);
    reinterpret_cast<float2*>(OUT)[n * 64 + l] = make_float2(fmaxf(o0, 0.f), fmaxf(o1, 0.f));
}

__global__ __launch_bounds__(64) void agg2_kernel(const unsigned int* __restrict__ H,   // bf16x2, ld=32
                                                  const int* __restrict__ row_start,
                                                  const unsigned short* __restrict__ csr_src,
                                                  const float* __restrict__ dinv,
                                                  const float* __restrict__ bias,
                                                  float* __restrict__ OUT) {
    int n = blockIdx.x;
    int l = threadIdx.x;
    int half = l >> 5;                  // lanes 0-31: even edges, 32-63: odd edges
    int c = l & 31;                     // channel pair {2c, 2c+1}
    float dn = dinv[n];
    unsigned int us = H[n * 32 + c];
    float a0 = half ? 0.f : dn * bflo(us);
    float a1 = half ? 0.f : dn * bfhi(us);
    float b0 = 0.f, b1 = 0.f;
    int e0 = row_start[n], e1 = row_start[n + 1];
    for (int base = e0; base < e1; base += 64) {
        int m = min(64, e1 - base);
        int sv = csr_src[base + min(l, m - 1)];
        float wv = (l < m) ? dinv[sv] : 0.f;
        int j = 0;
        for (; j + 4 <= m; j += 4) {    // per half-wave: 2 edges in flight (4 total)
            int jj0 = j + half, jj1 = j + 2 + half;
            int s0 = __shfl(sv, jj0), s1 = __shfl(sv, jj1);
            float w0 = __shfl(wv, jj0), w1 = __shfl(wv, jj1);
            unsigned int u0 = H[s0 * 32 + c];
            unsigned int u1 = H[s1 * 32 + c];
            a0 = fmaf(w0, bflo(u0), a0); a1 = fmaf(w0, bfhi(u0), a1);
            b0 = fmaf(w1, bflo(u1), b0); b1 = fmaf(w1, bfhi(u1), b1);
        }
        for (; j < m; j += 2) {
            int jj = j + half;
            int s = __shfl(sv, min(jj, m - 1));
            float w = __shfl(wv, jj);   // 0 when jj >= m (odd m, half=1)
            unsigned int u = H[s * 32 + c];
            a0 = fmaf(w, bflo(u), a0);
            a1 = fmaf(w, bfhi(u), a1);
        }
    }
    a0 += b0; a1 += b1;
    a0 += __shfl_xor(a0, 32);
    a1 += __shfl_xor(a1, 32);
    if (l < 32) {
        float2 bv = reinterpret_cast<const float2*>(bias)[c];
        float o0 = fmaf(dn, a0, bv.x);
        float o1 = fmaf(dn, a1, bv.y);
        reinterpret_cast<float2*>(OUT)[n * 32 + c] = make_float2(o0, o1);   // no ReLU
    }
}

// ---------------- launch ----------------

extern "C" void kernel_launch(void* const* d_in, const int* in_sizes, int n_in,
                              void* d_out, int out_size, void* d_ws, size_t ws_size,
                              hipStream_t stream) {
    const float* x  = (const float*)d_in[0];
    const int*   ei = (const int*)d_in[1];
    const float* W1 = (const float*)d_in[2];
    const float* b1 = (const float*)d_in[3];
    const float* W2 = (const float*)d_in[4];
    const float* b2 = (const float*)d_in[5];
    const int* srcI = ei;
    const int* dstI = ei + NE;
    float* out = (float*)d_out;

    char* ws = (char*)d_ws;
    size_t off = 0;
    auto take = [&](size_t bytes) {
        char* p = ws + off;
        off = (off + bytes + 255) & ~(size_t)255;
        return p;
    };
    int*            row_start     = (int*)take((size_t)(NN + 1) * 4);
    int*            bucket_cursor = (int*)take((size_t)NB * 4);
    int*            bucket_start  = (int*)take((size_t)(NB + 1) * 4);
    float*          dinv          = (float*)take((size_t)NN * 4);
    unsigned short* W1t_hi        = (unsigned short*)take((size_t)CH * CIN * 2);
    unsigned short* W1t_lo        = (unsigned short*)take((size_t)CH * CIN * 2);
    unsigned short* W2t_hi        = (unsigned short*)take((size_t)CO * CH * 2);
    unsigned short* W2t_lo        = (unsigned short*)take((size_t)CO * CH * 2);
    unsigned short* csr_src       = (unsigned short*)take((size_t)NE * 2);
    unsigned short* h1b           = (unsigned short*)take((size_t)NN * CH * 2);   // bf16
    float*          g1            = (float*)take((size_t)NN * CH * 4);            // fp32
    unsigned short* h2b           = (unsigned short*)take((size_t)NN * CO * 2);   // bf16
    // pairs aliases g1: pairs dead (after bucket_sort) before agg1 writes g1
    unsigned int*   pairs         = (unsigned int*)g1;   // NB*BUCKET_CAP*4 = 12.85 MB <= 25.6 MB

    wprep<<<(CIN * CH + CH * CO + 255) / 256, 256, 0, stream>>>(W1, W2, W1t_hi, W1t_lo,
                                                                W2t_hi, W2t_lo, bucket_cursor);
    fused_gemm1_scatter<<<SCAT_BLOCKS + G1_TILES, 256, 0, stream>>>(srcI, dstI, bucket_cursor,
                                                                    pairs, x, W1t_hi, W1t_lo, h1b);
    bucket_scan<<<1, 256, 0, stream>>>(bucket_cursor, bucket_start);
    bucket_sort<<<NB, 1024, 0, stream>>>(pairs, bucket_cursor, bucket_start,
                                         row_start, dinv, csr_src);

    agg1_kernel<<<NN, 64, 0, stream>>>((const unsigned int*)h1b, row_start, csr_src, dinv, b1, g1);
    gemm2_kernel<<<G2_TILES, 256, 0, stream>>>(g1, W2t_hi, W2t_lo, h2b);
    agg2_kernel<<<NN, 64, 0, stream>>>((const unsigned int*)h2b, row_start, csr_src, dinv, b2, out);
}

// Round 9
// 191.986 us; speedup vs baseline: 1.4064x; 1.4064x over previous
//
#include <hip/hip_runtime.h>

constexpr int NN  = 50000;
constexpr int NE  = 1600000;
constexpr int CIN = 384;
constexpr int CH  = 128;
constexpr int CO  = 64;

constexpr int NB = (NN + 255) / 256;              // 196 dst-buckets of 256 nodes
constexpr int BUCKET_CAP = 16384;                 // append region per bucket (mean 8163)
constexpr int SCAT_EPB     = 4096;                // 256 thr * 16 edges
constexpr int SCAT_BLOCKS  = (NE + SCAT_EPB - 1) / SCAT_EPB;     // 391
constexpr int G1_TILES     = (NN + 127) / 128;    // 391 blocks of 128 rows
constexpr int G2_TILES     = (NN + 127) / 128;    // 391

typedef __attribute__((ext_vector_type(8))) short short8;
typedef __attribute__((ext_vector_type(4))) float f32x4;

// ---------------- bf16 helpers ----------------

__device__ inline unsigned short f2bf(float f) {
    union { float f; unsigned int u; } v; v.f = f;
    unsigned int u = v.u + 0x7FFFu + ((v.u >> 16) & 1u);   // round-to-nearest-even
    return (unsigned short)(u >> 16);
}
__device__ inline float bf2f(unsigned short h) { return __uint_as_float((unsigned int)h << 16); }
__device__ inline float bflo(unsigned int u) { return __uint_as_float(u << 16); }
__device__ inline float bfhi(unsigned int u) { return __uint_as_float(u & 0xFFFF0000u); }

// convert 8 fp32 -> hi/lo bf16 short8
__device__ inline void cvt8(const float* f, short8& vh, short8& vl) {
    #pragma unroll
    for (int i = 0; i < 8; ++i) {
        unsigned short h = f2bf(f[i]);
        vh[i] = (short)h;
        vl[i] = (short)f2bf(f[i] - bf2f(h));
    }
}

// ---------------- W transpose + hi/lo bf16 split + cursor init ----------------

__global__ __launch_bounds__(256) void wprep(const float* __restrict__ W1, const float* __restrict__ W2,
                                             unsigned short* __restrict__ W1t_hi, unsigned short* __restrict__ W1t_lo,
                                             unsigned short* __restrict__ W2t_hi, unsigned short* __restrict__ W2t_lo,
                                             int* __restrict__ bucket_cursor) {
    int i = blockIdx.x * 256 + threadIdx.x;
    if (blockIdx.x == 0 && threadIdx.x < NB)
        bucket_cursor[threadIdx.x] = threadIdx.x * BUCKET_CAP;
    if (i < CIN * CH) {
        int k = i / CH, c = i % CH;
        float v = W1[i];
        unsigned short h = f2bf(v);
        W1t_hi[c * CIN + k] = h;
        W1t_lo[c * CIN + k] = f2bf(v - bf2f(h));
    } else if (i < CIN * CH + CH * CO) {
        int j = i - CIN * CH;
        int k = j / CO, c = j % CO;
        float v = W2[j];
        unsigned short h = f2bf(v);
        W2t_hi[c * CH + k] = h;
        W2t_lo[c * CH + k] = f2bf(v - bf2f(h));
    }
}

// ---------------- fused MFMA-GEMM1 (LDS-free) + bucketed edge scatter ----------------
// blocks [0, SCAT_BLOCKS): bin edges into per-bucket append regions (uses LDS hist).
// blocks [SCAT_BLOCKS, +G1_TILES): h1 = x @ W1, bf16 hi/lo MFMA, NO LDS/barriers.
// ALL acc-indexing loops fully unrolled (rule #20: partial unroll -> runtime
// index -> acc spills to scratch; this was round-8's 312MB-write regression).

__global__ __launch_bounds__(256, 2) void fused_gemm1_scatter(const int* __restrict__ src,
                                                              const int* __restrict__ dst,
                                                              int* __restrict__ bucket_cursor,
                                                              unsigned int* __restrict__ pairs,
                                                              const float* __restrict__ X,
                                                              const unsigned short* __restrict__ Wt_hi,
                                                              const unsigned short* __restrict__ Wt_lo,
                                                              unsigned short* __restrict__ Hb) {
    __shared__ int hist[NB];
    __shared__ int base_s[NB];

    int tid = threadIdx.x;
    if (blockIdx.x < SCAT_BLOCKS) {
        int e0 = blockIdx.x * SCAT_EPB;
        for (int i = tid; i < NB; i += 256) hist[i] = 0;
        __syncthreads();
        int key[16];
        unsigned int pay[16];
        #pragma unroll
        for (int k = 0; k < 16; ++k) {
            int e = e0 + k * 256 + tid;
            if (e < NE) {
                int s = src[e], d = dst[e];
                int b = d >> 8;
                int pos = atomicAdd(&hist[b], 1);
                key[k] = b | (pos << 8);
                pay[k] = (unsigned int)s | ((unsigned int)(d & 255) << 16);
            } else {
                key[k] = -1;
            }
        }
        __syncthreads();
        for (int i = tid; i < NB; i += 256)
            base_s[i] = hist[i] ? atomicAdd(&bucket_cursor[i], hist[i]) : 0;
        __syncthreads();
        #pragma unroll
        for (int k = 0; k < 16; ++k) {
            if (key[k] >= 0) {
                int b = key[k] & 255, pos = key[k] >> 8;
                pairs[base_s[b] + pos] = pay[k];
            }
        }
        return;
    }

    // ---- GEMM1: 128 rows x 128 cols per block, 4 waves x (32r x 128c) ----
    int wid = tid >> 6, lane = tid & 63;
    int row0 = (blockIdx.x - SCAT_BLOCKS) * 128;
    int r = lane & 15, ko = (lane >> 4) * 8;
    f32x4 acc[2][8] = {};

    int grow0 = row0 + wid * 32 + r;          // rt=0 row
    int grow1 = grow0 + 16;                   // rt=1 row
    const float* xp0 = X + (size_t)grow0 * CIN + ko;
    const float* xp1 = X + (size_t)grow1 * CIN + ko;
    bool ok0 = grow0 < NN, ok1 = grow1 < NN;

    #pragma unroll
    for (int kk = 0; kk < CIN / 32; ++kk) {
        int k0 = kk * 32;
        short8 a_hi[2], a_lo[2];
        {
            float f[8];
            if (ok0) {
                const float4* p = reinterpret_cast<const float4*>(xp0 + k0);
                float4 v0 = p[0], v1 = p[1];
                f[0]=v0.x; f[1]=v0.y; f[2]=v0.z; f[3]=v0.w;
                f[4]=v1.x; f[5]=v1.y; f[6]=v1.z; f[7]=v1.w;
            } else {
                #pragma unroll
                for (int i = 0; i < 8; ++i) f[i] = 0.f;
            }
            cvt8(f, a_hi[0], a_lo[0]);
            if (ok1) {
                const float4* p = reinterpret_cast<const float4*>(xp1 + k0);
                float4 v0 = p[0], v1 = p[1];
                f[0]=v0.x; f[1]=v0.y; f[2]=v0.z; f[3]=v0.w;
                f[4]=v1.x; f[5]=v1.y; f[6]=v1.z; f[7]=v1.w;
            } else {
                #pragma unroll
                for (int i = 0; i < 8; ++i) f[i] = 0.f;
            }
            cvt8(f, a_hi[1], a_lo[1]);
        }
        const unsigned short* wh = Wt_hi + (size_t)r * CIN + k0 + ko;
        const unsigned short* wl = Wt_lo + (size_t)r * CIN + k0 + ko;
        #pragma unroll
        for (int ct = 0; ct < 8; ++ct) {
            short8 b_hi = *reinterpret_cast<const short8*>(wh + (size_t)ct * 16 * CIN);
            short8 b_lo = *reinterpret_cast<const short8*>(wl + (size_t)ct * 16 * CIN);
            #pragma unroll
            for (int rt = 0; rt < 2; ++rt) {
                acc[rt][ct] = __builtin_amdgcn_mfma_f32_16x16x32_bf16(a_hi[rt], b_hi, acc[rt][ct], 0, 0, 0);
                acc[rt][ct] = __builtin_amdgcn_mfma_f32_16x16x32_bf16(a_hi[rt], b_lo, acc[rt][ct], 0, 0, 0);
                acc[rt][ct] = __builtin_amdgcn_mfma_f32_16x16x32_bf16(a_lo[rt], b_hi, acc[rt][ct], 0, 0, 0);
            }
        }
    }
    // epilogue: D row=(lane>>4)*4+j, col=lane&15 per 16x16 tile
    int cl = lane & 15, rg = lane >> 4;
    #pragma unroll
    for (int rt = 0; rt < 2; ++rt) {
        #pragma unroll
        for (int j = 0; j < 4; ++j) {
            int row = row0 + wid * 32 + rt * 16 + rg * 4 + j;
            if (row < NN) {
                unsigned short* hp = Hb + (size_t)row * CH + cl;
                #pragma unroll
                for (int ct = 0; ct < 8; ++ct)
                    hp[ct * 16] = f2bf(acc[rt][ct][j]);
            }
        }
    }
}

// ---------------- bucket totals -> exclusive scan ----------------

__global__ __launch_bounds__(256) void bucket_scan(const int* __restrict__ bucket_cursor,
                                                   int* __restrict__ bucket_start) {
    __shared__ int tmp[256];
    int t = threadIdx.x;
    int v = (t < NB) ? (bucket_cursor[t] - t * BUCKET_CAP) : 0;
    tmp[t] = v;
    __syncthreads();
    for (int off = 1; off < 256; off <<= 1) {
        int add = (t >= off) ? tmp[t - off] : 0;
        __syncthreads();
        tmp[t] += add;
        __syncthreads();
    }
    if (t < NB) bucket_start[t] = tmp[t] - v;
    if (t == NB - 1) bucket_start[NB] = tmp[t];   // == NE
}

// ---------------- in-bucket count + sort -> CSR, row_start, dinv ----------------

__global__ __launch_bounds__(1024) void bucket_sort(const unsigned int* __restrict__ pairs,
                                                    const int* __restrict__ bucket_cursor,
                                                    const int* __restrict__ bucket_start,
                                                    int* __restrict__ row_start,
                                                    float* __restrict__ dinv,
                                                    unsigned short* __restrict__ csr_src) {
    __shared__ int cnt[256];
    __shared__ int pref[256];
    __shared__ int cur[256];
    int b = blockIdx.x, t = threadIdx.x;
    int p0 = b * BUCKET_CAP;
    int ne = bucket_cursor[b] - p0;
    int out0 = bucket_start[b];
    if (t < 256) cnt[t] = 0;
    __syncthreads();
    for (int i = t; i < ne; i += 1024)
        atomicAdd(&cnt[(pairs[p0 + i] >> 16) & 255], 1);
    __syncthreads();
    if (t < 256) pref[t] = cnt[t];
    __syncthreads();
    for (int off = 1; off < 256; off <<= 1) {
        int add = (t < 256 && t >= off) ? pref[t - off] : 0;
        __syncthreads();
        if (t < 256) pref[t] += add;
        __syncthreads();
    }
    if (t < 256) {
        int n = (b << 8) + t;
        if (n < NN) {
            int rs = out0 + pref[t] - cnt[t];
            row_start[n] = rs;
            cur[t] = rs;
            dinv[n] = rsqrtf((float)(cnt[t] + 1));  // + self-loop
        }
    }
    if (b == NB - 1 && t == 0) row_start[NN] = NE;
    __syncthreads();
    for (int i = t; i < ne; i += 1024) {
        unsigned int p = pairs[p0 + i];
        int pos = atomicAdd(&cur[(p >> 16) & 255], 1);
        csr_src[pos] = (unsigned short)(p & 0xFFFF);
    }
}

// ---------------- MFMA GEMM2 (LDS-free): h2 = g1 @ W2, bf16 out ----------------

__global__ __launch_bounds__(256, 2) void gemm2_kernel(const float* __restrict__ X,
                                                       const unsigned short* __restrict__ Wt_hi,
                                                       const unsigned short* __restrict__ Wt_lo,
                                                       unsigned short* __restrict__ Hb) {
    int tid = threadIdx.x;
    int wid = tid >> 6, lane = tid & 63;
    int row0 = blockIdx.x * 128;
    int r = lane & 15, ko = (lane >> 4) * 8;
    f32x4 acc[2][4] = {};

    int grow0 = row0 + wid * 32 + r;
    int grow1 = grow0 + 16;
    const float* xp0 = X + (size_t)grow0 * CH + ko;
    const float* xp1 = X + (size_t)grow1 * CH + ko;
    bool ok0 = grow0 < NN, ok1 = grow1 < NN;

    #pragma unroll
    for (int kk = 0; kk < CH / 32; ++kk) {
        int k0 = kk * 32;
        short8 a_hi[2], a_lo[2];
        {
            float f[8];
            if (ok0) {
                const float4* p = reinterpret_cast<const float4*>(xp0 + k0);
                float4 v0 = p[0], v1 = p[1];
                f[0]=v0.x; f[1]=v0.y; f[2]=v0.z; f[3]=v0.w;
                f[4]=v1.x; f[5]=v1.y; f[6]=v1.z; f[7]=v1.w;
            } else {
                #pragma unroll
                for (int i = 0; i < 8; ++i) f[i] = 0.f;
            }
            cvt8(f, a_hi[0], a_lo[0]);
            if (ok1) {
                const float4* p = reinterpret_cast<const float4*>(xp1 + k0);
                float4 v0 = p[0], v1 = p[1];
                f[0]=v0.x; f[1]=v0.y; f[2]=v0.z; f[3]=v0.w;
                f[4]=v1.x; f[5]=v1.y; f[6]=v1.z; f[7]=v1.w;
            } else {
                #pragma unroll
                for (int i = 0; i < 8; ++i) f[i] = 0.f;
            }
            cvt8(f, a_hi[1], a_lo[1]);
        }
        const unsigned short* wh = Wt_hi + (size_t)r * CH + k0 + ko;
        const unsigned short* wl = Wt_lo + (size_t)r * CH + k0 + ko;
        #pragma unroll
        for (int ct = 0; ct < 4; ++ct) {
            short8 b_hi = *reinterpret_cast<const short8*>(wh + (size_t)ct * 16 * CH);
            short8 b_lo = *reinterpret_cast<const short8*>(wl + (size_t)ct * 16 * CH);
            #pragma unroll
            for (int rt = 0; rt < 2; ++rt) {
                acc[rt][ct] = __builtin_amdgcn_mfma_f32_16x16x32_bf16(a_hi[rt], b_hi, acc[rt][ct], 0, 0, 0);
                acc[rt][ct] = __builtin_amdgcn_mfma_f32_16x16x32_bf16(a_hi[rt], b_lo, acc[rt][ct], 0, 0, 0);
                acc[rt][ct] = __builtin_amdgcn_mfma_f32_16x16x32_bf16(a_lo[rt], b_hi, acc[rt][ct], 0, 0, 0);
            }
        }
    }
    int cl = lane & 15, rg = lane >> 4;
    #pragma unroll
    for (int rt = 0; rt < 2; ++rt) {
        #pragma unroll
        for (int j = 0; j < 4; ++j) {
            int row = row0 + wid * 32 + rt * 16 + rg * 4 + j;
            if (row < NN) {
                unsigned short* hp = Hb + (size_t)row * CO + cl;
                #pragma unroll
                for (int ct = 0; ct < 4; ++ct)
                    hp[ct * 16] = f2bf(acc[rt][ct][j]);
            }
        }
    }
}

// ---------------- CSR gather-aggregation (bf16, 1 wave/node, 4 edges in flight) ----------------

__global__ __launch_bounds__(64) void agg1_kernel(const unsigned int* __restrict__ H,   // bf16x2, ld=64
                                                  const int* __restrict__ row_start,
                                                  const unsigned short* __restrict__ csr_src,
                                                  const float* __restrict__ dinv,
                                                  const float* __restrict__ bias,
                                                  float* __restrict__ OUT) {
    int n = blockIdx.x;
    int l = threadIdx.x;                // lane = channel pair {2l, 2l+1}
    float dn = dinv[n];
    unsigned int us = H[n * 64 + l];
    float a0 = dn * bflo(us), a1 = dn * bfhi(us);   // self-loop
    float b0 = 0.f, b1 = 0.f, c0 = 0.f, c1 = 0.f, d0 = 0.f, d1 = 0.f;
    int e0 = row_start[n], e1 = row_start[n + 1];
    for (int base = e0; base < e1; base += 64) {
        int m = min(64, e1 - base);
        int sv = csr_src[base + min(l, m - 1)];
        float wv = (l < m) ? dinv[sv] : 0.f;
        int j = 0;
        for (; j + 4 <= m; j += 4) {    // 4 independent row-gathers in flight
            int s0 = __shfl(sv, j),     s1 = __shfl(sv, j + 1);
            int s2 = __shfl(sv, j + 2), s3 = __shfl(sv, j + 3);
            float w0 = __shfl(wv, j),     w1 = __shfl(wv, j + 1);
            float w2 = __shfl(wv, j + 2), w3 = __shfl(wv, j + 3);
            unsigned int u0 = H[s0 * 64 + l];
            unsigned int u1 = H[s1 * 64 + l];
            unsigned int u2 = H[s2 * 64 + l];
            unsigned int u3 = H[s3 * 64 + l];
            a0 = fmaf(w0, bflo(u0), a0); a1 = fmaf(w0, bfhi(u0), a1);
            b0 = fmaf(w1, bflo(u1), b0); b1 = fmaf(w1, bfhi(u1), b1);
            c0 = fmaf(w2, bflo(u2), c0); c1 = fmaf(w2, bfhi(u2), c1);
            d0 = fmaf(w3, bflo(u3), d0); d1 = fmaf(w3, bfhi(u3), d1);
        }
        for (; j < m; ++j) {
            int s0 = __shfl(sv, j);
            float w0 = __shfl(wv, j);
            unsigned int u0 = H[s0 * 64 + l];
            a0 = fmaf(w0, bflo(u0), a0); a1 = fmaf(w0, bfhi(u0), a1);
        }
    }
    float o0 = fmaf(dn, (a0 + b0) + (c0 + d0), reinterpret_cast<const float2*>(bias)[l].x);
    float o1 = fmaf(dn, (a1 + b1) + (c1 + d1), reinterpret_cast<const float2*>(bias)[l].y);
    reinterpret_cast<float2*>(OUT)[n * 64 + l] = make_float2(fmaxf(o0, 0.f), fmaxf(o1, 0.f));
}

__global__ __launch_bounds__(64) void agg2_kernel(const unsigned int* __restrict__ H,   // bf16x2, ld=32
                                                  const int* __restrict__ row_start,
                                                  const unsigned short* __restrict__ csr_src,
                                                  const float* __restrict__ dinv,
                                                  const float* __restrict__ bias,
                                                  float* __restrict__ OUT) {
    int n = blockIdx.x;
    int l = threadIdx.x;
    int half = l >> 5;                  // lanes 0-31: even edges, 32-63: odd edges
    int c = l & 31;                     // channel pair {2c, 2c+1}
    float dn = dinv[n];
    unsigned int us = H[n * 32 + c];
    float a0 = half ? 0.f : dn * bflo(us);
    float a1 = half ? 0.f : dn * bfhi(us);
    float b0 = 0.f, b1 = 0.f;
    int e0 = row_start[n], e1 = row_start[n + 1];
    for (int base = e0; base < e1; base += 64) {
        int m = min(64, e1 - base);
        int sv = csr_src[base + min(l, m - 1)];
        float wv = (l < m) ? dinv[sv] : 0.f;
        int j = 0;
        for (; j + 4 <= m; j += 4) {    // per half-wave: 2 edges in flight (4 total)
            int jj0 = j + half, jj1 = j + 2 + half;
            int s0 = __shfl(sv, jj0), s1 = __shfl(sv, jj1);
            float w0 = __shfl(wv, jj0), w1 = __shfl(wv, jj1);
            unsigned int u0 = H[s0 * 32 + c];
            unsigned int u1 = H[s1 * 32 + c];
            a0 = fmaf(w0, bflo(u0), a0); a1 = fmaf(w0, bfhi(u0), a1);
            b0 = fmaf(w1, bflo(u1), b0); b1 = fmaf(w1, bfhi(u1), b1);
        }
        for (; j < m; j += 2) {
            int jj = j + half;
            int s = __shfl(sv, min(jj, m - 1));
            float w = __shfl(wv, jj);   // 0 when jj >= m (odd m, half=1)
            unsigned int u = H[s * 32 + c];
            a0 = fmaf(w, bflo(u), a0);
            a1 = fmaf(w, bfhi(u), a1);
        }
    }
    a0 += b0; a1 += b1;
    a0 += __shfl_xor(a0, 32);
    a1 += __shfl_xor(a1, 32);
    if (l < 32) {
        float2 bv = reinterpret_cast<const float2*>(bias)[c];
        float o0 = fmaf(dn, a0, bv.x);
        float o1 = fmaf(dn, a1, bv.y);
        reinterpret_cast<float2*>(OUT)[n * 32 + c] = make_float2(o0, o1);   // no ReLU
    }
}

// ---------------- launch ----------------

extern "C" void kernel_launch(void* const* d_in, const int* in_sizes, int n_in,
                              void* d_out, int out_size, void* d_ws, size_t ws_size,
                              hipStream_t stream) {
    const float* x  = (const float*)d_in[0];
    const int*   ei = (const int*)d_in[1];
    const float* W1 = (const float*)d_in[2];
    const float* b1 = (const float*)d_in[3];
    const float* W2 = (const float*)d_in[4];
    const float* b2 = (const float*)d_in[5];
    const int* srcI = ei;
    const int* dstI = ei + NE;
    float* out = (float*)d_out;

    char* ws = (char*)d_ws;
    size_t off = 0;
    auto take = [&](size_t bytes) {
        char* p = ws + off;
        off = (off + bytes + 255) & ~(size_t)255;
        return p;
    };
    int*            row_start     = (int*)take((size_t)(NN + 1) * 4);
    int*            bucket_cursor = (int*)take((size_t)NB * 4);
    int*            bucket_start  = (int*)take((size_t)(NB + 1) * 4);
    float*          dinv          = (float*)take((size_t)NN * 4);
    unsigned short* W1t_hi        = (unsigned short*)take((size_t)CH * CIN * 2);
    unsigned short* W1t_lo        = (unsigned short*)take((size_t)CH * CIN * 2);
    unsigned short* W2t_hi        = (unsigned short*)take((size_t)CO * CH * 2);
    unsigned short* W2t_lo        = (unsigned short*)take((size_t)CO * CH * 2);
    unsigned short* csr_src       = (unsigned short*)take((size_t)NE * 2);
    unsigned short* h1b           = (unsigned short*)take((size_t)NN * CH * 2);   // bf16
    float*          g1            = (float*)take((size_t)NN * CH * 4);            // fp32
    unsigned short* h2b           = (unsigned short*)take((size_t)NN * CO * 2);   // bf16
    // pairs aliases g1: pairs dead (after bucket_sort) before agg1 writes g1
    unsigned int*   pairs         = (unsigned int*)g1;   // NB*BUCKET_CAP*4 = 12.85 MB <= 25.6 MB

    wprep<<<(CIN * CH + CH * CO + 255) / 256, 256, 0, stream>>>(W1, W2, W1t_hi, W1t_lo,
                                                                W2t_hi, W2t_lo, bucket_cursor);
    fused_gemm1_scatter<<<SCAT_BLOCKS + G1_TILES, 256, 0, stream>>>(srcI, dstI, bucket_cursor,
                                                                    pairs, x, W1t_hi, W1t_lo, h1b);
    bucket_scan<<<1, 256, 0, stream>>>(bucket_cursor, bucket_start);
    bucket_sort<<<NB, 1024, 0, stream>>>(pairs, bucket_cursor, bucket_start,
                                         row_start, dinv, csr_src);

    agg1_kernel<<<NN, 64, 0, stream>>>((const unsigned int*)h1b, row_start, csr_src, dinv, b1, g1);
    gemm2_kernel<<<G2_TILES, 256, 0, stream>>>(g1, W2t_hi, W2t_lo, h2b);
    agg2_kernel<<<NN, 64, 0, stream>>>((const unsigned int*)h2b, row_start, csr_src, dinv, b2, out);
}

// Round 10
// 170.199 us; speedup vs baseline: 1.5865x; 1.1280x over previous
//
#include <hip/hip_runtime.h>

constexpr int NN  = 50000;
constexpr int NE  = 1600000;
constexpr int CIN = 384;
constexpr int CH  = 128;
constexpr int CO  = 64;

constexpr int NB = (NN + 255) / 256;              // 196 dst-buckets of 256 nodes
constexpr int BUCKET_CAP = 16384;                 // append region per bucket (mean 8163)
constexpr int SCAT_EPB     = 4096;                // 256 thr * 16 edges
constexpr int SCAT_BLOCKS  = (NE + SCAT_EPB - 1) / SCAT_EPB;     // 391
constexpr int G1_TILES     = (NN + 63) / 64;      // 782 blocks of 64 rows
constexpr int G2_TILES     = (NN + 63) / 64;      // 782

typedef __attribute__((ext_vector_type(8))) short short8;
typedef __attribute__((ext_vector_type(4))) float f32x4;

// ---------------- bf16 helpers ----------------

__device__ inline unsigned short f2bf(float f) {
    union { float f; unsigned int u; } v; v.f = f;
    unsigned int u = v.u + 0x7FFFu + ((v.u >> 16) & 1u);   // round-to-nearest-even
    return (unsigned short)(u >> 16);
}
__device__ inline float bf2f(unsigned short h) { return __uint_as_float((unsigned int)h << 16); }
__device__ inline float bflo(unsigned int u) { return __uint_as_float(u << 16); }
__device__ inline float bfhi(unsigned int u) { return __uint_as_float(u & 0xFFFF0000u); }

// convert 8 fp32 -> hi/lo bf16 short8 (all indices compile-time)
__device__ inline void cvt8(const float* f, short8& vh, short8& vl) {
    #pragma unroll
    for (int i = 0; i < 8; ++i) {
        unsigned short h = f2bf(f[i]);
        vh[i] = (short)h;
        vl[i] = (short)f2bf(f[i] - bf2f(h));
    }
}

// ---------------- W transpose + hi/lo bf16 split + cursor init ----------------

__global__ __launch_bounds__(256) void wprep(const float* __restrict__ W1, const float* __restrict__ W2,
                                             unsigned short* __restrict__ W1t_hi, unsigned short* __restrict__ W1t_lo,
                                             unsigned short* __restrict__ W2t_hi, unsigned short* __restrict__ W2t_lo,
                                             int* __restrict__ bucket_cursor) {
    int i = blockIdx.x * 256 + threadIdx.x;
    if (blockIdx.x == 0 && threadIdx.x < NB)
        bucket_cursor[threadIdx.x] = threadIdx.x * BUCKET_CAP;
    if (i < CIN * CH) {
        int k = i / CH, c = i % CH;
        float v = W1[i];
        unsigned short h = f2bf(v);
        W1t_hi[c * CIN + k] = h;
        W1t_lo[c * CIN + k] = f2bf(v - bf2f(h));
    } else if (i < CIN * CH + CH * CO) {
        int j = i - CIN * CH;
        int k = j / CO, c = j % CO;
        float v = W2[j];
        unsigned short h = f2bf(v);
        W2t_hi[c * CH + k] = h;
        W2t_lo[c * CH + k] = f2bf(v - bf2f(h));
    }
}

// ---------------- fused MFMA-GEMM1 (A direct, W in LDS) + bucketed scatter ----------------
// blocks [0, SCAT_BLOCKS): bin edges into per-bucket append regions.
// blocks [SCAT_BLOCKS, +G1_TILES): h1 = x @ W1. 64-row tiles (782 blocks ->
// ~3 waves/SIMD; r9 was grid-limited at 1.5). A rows wave-private: per-lane
// fp32 global loads + reg cvt. W hi/lo staged in LDS per k-step (shared by
// 4 waves). T14: next k-step's A+W global loads issued under current MFMA.

__global__ __launch_bounds__(256, 3) void fused_gemm1_scatter(const int* __restrict__ src,
                                                              const int* __restrict__ dst,
                                                              int* __restrict__ bucket_cursor,
                                                              unsigned int* __restrict__ pairs,
                                                              const float* __restrict__ X,
                                                              const unsigned short* __restrict__ Wt_hi,
                                                              const unsigned short* __restrict__ Wt_lo,
                                                              unsigned short* __restrict__ Hb) {
    __shared__ unsigned short ws[2][128][40];   // [hi/lo][col][k], stride 40
    __shared__ int hist[NB];
    __shared__ int base_s[NB];

    int tid = threadIdx.x;
    if (blockIdx.x < SCAT_BLOCKS) {
        int e0 = blockIdx.x * SCAT_EPB;
        for (int i = tid; i < NB; i += 256) hist[i] = 0;
        __syncthreads();
        int key[16];
        unsigned int pay[16];
        #pragma unroll
        for (int k = 0; k < 16; ++k) {
            int e = e0 + k * 256 + tid;
            if (e < NE) {
                int s = src[e], d = dst[e];
                int b = d >> 8;
                int pos = atomicAdd(&hist[b], 1);
                key[k] = b | (pos << 8);
                pay[k] = (unsigned int)s | ((unsigned int)(d & 255) << 16);
            } else {
                key[k] = -1;
            }
        }
        __syncthreads();
        for (int i = tid; i < NB; i += 256)
            base_s[i] = hist[i] ? atomicAdd(&bucket_cursor[i], hist[i]) : 0;
        __syncthreads();
        #pragma unroll
        for (int k = 0; k < 16; ++k) {
            if (key[k] >= 0) {
                int b = key[k] & 255, pos = key[k] >> 8;
                pairs[base_s[b] + pos] = pay[k];
            }
        }
        return;
    }

    // ---- GEMM1: 64 rows x 128 cols per block, 4 waves x (16r x 128c) ----
    int wid = tid >> 6, lane = tid & 63;
    int row0 = (blockIdx.x - SCAT_BLOCKS) * 64;
    int r = lane & 15, ko = (lane >> 4) * 8;
    f32x4 acc[8] = {};

    int grow = row0 + wid * 16 + r;
    const float* xp = X + (size_t)grow * CIN + ko;
    bool ok = grow < NN;

    // W staging assignment: thread -> (table, col), 64B = full 32-k row chunk
    int stbl = tid >> 7, scol = tid & 127;
    const unsigned short* wsrc = (stbl ? Wt_lo : Wt_hi) + (size_t)scol * CIN;

    // prologue: prefetch k-step 0
    float fA[8];
    short8 w0, w1, w2, w3;
    {
        if (ok) {
            const float4* p = reinterpret_cast<const float4*>(xp);
            float4 v0 = p[0], v1 = p[1];
            fA[0]=v0.x; fA[1]=v0.y; fA[2]=v0.z; fA[3]=v0.w;
            fA[4]=v1.x; fA[5]=v1.y; fA[6]=v1.z; fA[7]=v1.w;
        } else {
            #pragma unroll
            for (int i = 0; i < 8; ++i) fA[i] = 0.f;
        }
        w0 = *reinterpret_cast<const short8*>(wsrc + 0);
        w1 = *reinterpret_cast<const short8*>(wsrc + 8);
        w2 = *reinterpret_cast<const short8*>(wsrc + 16);
        w3 = *reinterpret_cast<const short8*>(wsrc + 24);
    }

    for (int kk = 0; kk < CIN / 32; ++kk) {
        // stage W(kk) from prefetched regs
        *reinterpret_cast<short8*>(&ws[stbl][scol][0])  = w0;
        *reinterpret_cast<short8*>(&ws[stbl][scol][8])  = w1;
        *reinterpret_cast<short8*>(&ws[stbl][scol][16]) = w2;
        *reinterpret_cast<short8*>(&ws[stbl][scol][24]) = w3;
        __syncthreads();

        // T14: issue next k-step's global loads under this k-step's MFMAs
        float nA[8];
        short8 n0, n1, n2, n3;
        if (kk + 1 < CIN / 32) {
            int k1 = (kk + 1) * 32;
            if (ok) {
                const float4* p = reinterpret_cast<const float4*>(xp + k1);
                float4 v0 = p[0], v1 = p[1];
                nA[0]=v0.x; nA[1]=v0.y; nA[2]=v0.z; nA[3]=v0.w;
                nA[4]=v1.x; nA[5]=v1.y; nA[6]=v1.z; nA[7]=v1.w;
            } else {
                #pragma unroll
                for (int i = 0; i < 8; ++i) nA[i] = 0.f;
            }
            n0 = *reinterpret_cast<const short8*>(wsrc + k1 + 0);
            n1 = *reinterpret_cast<const short8*>(wsrc + k1 + 8);
            n2 = *reinterpret_cast<const short8*>(wsrc + k1 + 16);
            n3 = *reinterpret_cast<const short8*>(wsrc + k1 + 24);
        }

        short8 a_hi, a_lo;
        cvt8(fA, a_hi, a_lo);

        #pragma unroll
        for (int ct = 0; ct < 8; ++ct) {
            short8 b_hi = *reinterpret_cast<const short8*>(&ws[0][ct * 16 + r][ko]);
            short8 b_lo = *reinterpret_cast<const short8*>(&ws[1][ct * 16 + r][ko]);
            acc[ct] = __builtin_amdgcn_mfma_f32_16x16x32_bf16(a_hi, b_hi, acc[ct], 0, 0, 0);
            acc[ct] = __builtin_amdgcn_mfma_f32_16x16x32_bf16(a_hi, b_lo, acc[ct], 0, 0, 0);
            acc[ct] = __builtin_amdgcn_mfma_f32_16x16x32_bf16(a_lo, b_hi, acc[ct], 0, 0, 0);
        }
        __syncthreads();

        #pragma unroll
        for (int i = 0; i < 8; ++i) fA[i] = nA[i];
        w0 = n0; w1 = n1; w2 = n2; w3 = n3;
    }

    // epilogue: D row=(lane>>4)*4+j, col=lane&15 per 16x16 tile
    int cl = lane & 15, rg = lane >> 4;
    #pragma unroll
    for (int j = 0; j < 4; ++j) {
        int row = row0 + wid * 16 + rg * 4 + j;
        if (row < NN) {
            unsigned short* hp = Hb + (size_t)row * CH + cl;
            #pragma unroll
            for (int ct = 0; ct < 8; ++ct)
                hp[ct * 16] = f2bf(acc[ct][j]);
        }
    }
}

// ---------------- bucket totals -> exclusive scan ----------------

__global__ __launch_bounds__(256) void bucket_scan(const int* __restrict__ bucket_cursor,
                                                   int* __restrict__ bucket_start) {
    __shared__ int tmp[256];
    int t = threadIdx.x;
    int v = (t < NB) ? (bucket_cursor[t] - t * BUCKET_CAP) : 0;
    tmp[t] = v;
    __syncthreads();
    for (int off = 1; off < 256; off <<= 1) {
        int add = (t >= off) ? tmp[t - off] : 0;
        __syncthreads();
        tmp[t] += add;
        __syncthreads();
    }
    if (t < NB) bucket_start[t] = tmp[t] - v;
    if (t == NB - 1) bucket_start[NB] = tmp[t];   // == NE
}

// ---------------- in-bucket count + sort -> CSR, row_start, dinv ----------------

__global__ __launch_bounds__(1024) void bucket_sort(const unsigned int* __restrict__ pairs,
                                                    const int* __restrict__ bucket_cursor,
                                                    const int* __restrict__ bucket_start,
                                                    int* __restrict__ row_start,
                                                    float* __restrict__ dinv,
                                                    unsigned short* __restrict__ csr_src) {
    __shared__ int cnt[256];
    __shared__ int pref[256];
    __shared__ int cur[256];
    int b = blockIdx.x, t = threadIdx.x;
    int p0 = b * BUCKET_CAP;
    int ne = bucket_cursor[b] - p0;
    int out0 = bucket_start[b];
    if (t < 256) cnt[t] = 0;
    __syncthreads();
    for (int i = t; i < ne; i += 1024)
        atomicAdd(&cnt[(pairs[p0 + i] >> 16) & 255], 1);
    __syncthreads();
    if (t < 256) pref[t] = cnt[t];
    __syncthreads();
    for (int off = 1; off < 256; off <<= 1) {
        int add = (t < 256 && t >= off) ? pref[t - off] : 0;
        __syncthreads();
        if (t < 256) pref[t] += add;
        __syncthreads();
    }
    if (t < 256) {
        int n = (b << 8) + t;
        if (n < NN) {
            int rs = out0 + pref[t] - cnt[t];
            row_start[n] = rs;
            cur[t] = rs;
            dinv[n] = rsqrtf((float)(cnt[t] + 1));  // + self-loop
        }
    }
    if (b == NB - 1 && t == 0) row_start[NN] = NE;
    __syncthreads();
    for (int i = t; i < ne; i += 1024) {
        unsigned int p = pairs[p0 + i];
        int pos = atomicAdd(&cur[(p >> 16) & 255], 1);
        csr_src[pos] = (unsigned short)(p & 0xFFFF);
    }
}

// ---------------- MFMA GEMM2 (A direct, W2 in LDS): h2 = g1 @ W2 ----------------

__global__ __launch_bounds__(256, 3) void gemm2_kernel(const float* __restrict__ X,
                                                       const unsigned short* __restrict__ Wt_hi,
                                                       const unsigned short* __restrict__ Wt_lo,
                                                       unsigned short* __restrict__ Hb) {
    __shared__ unsigned short ws[2][64][40];
    int tid = threadIdx.x;
    int wid = tid >> 6, lane = tid & 63;
    int row0 = blockIdx.x * 64;
    int r = lane & 15, ko = (lane >> 4) * 8;
    f32x4 acc[4] = {};

    int grow = row0 + wid * 16 + r;
    const float* xp = X + (size_t)grow * CH + ko;
    bool ok = grow < NN;

    int stbl = tid >> 6 & 1, scol = tid & 63;      // threads 0..127 stage; others idle
    bool stager = tid < 128;
    const unsigned short* wsrc = (stbl ? Wt_lo : Wt_hi) + (size_t)scol * CH;

    float fA[8];
    short8 w0, w1, w2, w3;
    {
        if (ok) {
            const float4* p = reinterpret_cast<const float4*>(xp);
            float4 v0 = p[0], v1 = p[1];
            fA[0]=v0.x; fA[1]=v0.y; fA[2]=v0.z; fA[3]=v0.w;
            fA[4]=v1.x; fA[5]=v1.y; fA[6]=v1.z; fA[7]=v1.w;
        } else {
            #pragma unroll
            for (int i = 0; i < 8; ++i) fA[i] = 0.f;
        }
        if (stager) {
            w0 = *reinterpret_cast<const short8*>(wsrc + 0);
            w1 = *reinterpret_cast<const short8*>(wsrc + 8);
            w2 = *reinterpret_cast<const short8*>(wsrc + 16);
            w3 = *reinterpret_cast<const short8*>(wsrc + 24);
        }
    }

    for (int kk = 0; kk < CH / 32; ++kk) {
        if (stager) {
            *reinterpret_cast<short8*>(&ws[stbl][scol][0])  = w0;
            *reinterpret_cast<short8*>(&ws[stbl][scol][8])  = w1;
            *reinterpret_cast<short8*>(&ws[stbl][scol][16]) = w2;
            *reinterpret_cast<short8*>(&ws[stbl][scol][24]) = w3;
        }
        __syncthreads();

        float nA[8];
        short8 n0, n1, n2, n3;
        if (kk + 1 < CH / 32) {
            int k1 = (kk + 1) * 32;
            if (ok) {
                const float4* p = reinterpret_cast<const float4*>(xp + k1);
                float4 v0 = p[0], v1 = p[1];
                nA[0]=v0.x; nA[1]=v0.y; nA[2]=v0.z; nA[3]=v0.w;
                nA[4]=v1.x; nA[5]=v1.y; nA[6]=v1.z; nA[7]=v1.w;
            } else {
                #pragma unroll
                for (int i = 0; i < 8; ++i) nA[i] = 0.f;
            }
            if (stager) {
                n0 = *reinterpret_cast<const short8*>(wsrc + k1 + 0);
                n1 = *reinterpret_cast<const short8*>(wsrc + k1 + 8);
                n2 = *reinterpret_cast<const short8*>(wsrc + k1 + 16);
                n3 = *reinterpret_cast<const short8*>(wsrc + k1 + 24);
            }
        }

        short8 a_hi, a_lo;
        cvt8(fA, a_hi, a_lo);

        #pragma unroll
        for (int ct = 0; ct < 4; ++ct) {
            short8 b_hi = *reinterpret_cast<const short8*>(&ws[0][ct * 16 + r][ko]);
            short8 b_lo = *reinterpret_cast<const short8*>(&ws[1][ct * 16 + r][ko]);
            acc[ct] = __builtin_amdgcn_mfma_f32_16x16x32_bf16(a_hi, b_hi, acc[ct], 0, 0, 0);
            acc[ct] = __builtin_amdgcn_mfma_f32_16x16x32_bf16(a_hi, b_lo, acc[ct], 0, 0, 0);
            acc[ct] = __builtin_amdgcn_mfma_f32_16x16x32_bf16(a_lo, b_hi, acc[ct], 0, 0, 0);
        }
        __syncthreads();

        #pragma unroll
        for (int i = 0; i < 8; ++i) fA[i] = nA[i];
        w0 = n0; w1 = n1; w2 = n2; w3 = n3;
    }

    int cl = lane & 15, rg = lane >> 4;
    #pragma unroll
    for (int j = 0; j < 4; ++j) {
        int row = row0 + wid * 16 + rg * 4 + j;
        if (row < NN) {
            unsigned short* hp = Hb + (size_t)row * CO + cl;
            #pragma unroll
            for (int ct = 0; ct < 4; ++ct)
                hp[ct * 16] = f2bf(acc[ct][j]);
        }
    }
}

// ---------------- CSR gather-aggregation (bf16, 1 wave/node, 4 edges in flight) ----------------

__global__ __launch_bounds__(64) void agg1_kernel(const unsigned int* __restrict__ H,   // bf16x2, ld=64
                                                  const int* __restrict__ row_start,
                                                  const unsigned short* __restrict__ csr_src,
                                                  const float* __restrict__ dinv,
                                                  const float* __restrict__ bias,
                                                  float* __restrict__ OUT) {
    int n = blockIdx.x;
    int l = threadIdx.x;                // lane = channel pair {2l, 2l+1}
    float dn = dinv[n];
    unsigned int us = H[n * 64 + l];
    float a0 = dn * bflo(us), a1 = dn * bfhi(us);   // self-loop
    float b0 = 0.f, b1 = 0.f, c0 = 0.f, c1 = 0.f, d0 = 0.f, d1 = 0.f;
    int e0 = row_start[n], e1 = row_start[n + 1];
    for (int base = e0; base < e1; base += 64) {
        int m = min(64, e1 - base);
        int sv = csr_src[base + min(l, m - 1)];
        float wv = (l < m) ? dinv[sv] : 0.f;
        int j = 0;
        for (; j + 4 <= m; j += 4) {    // 4 independent row-gathers in flight
            int s0 = __shfl(sv, j),     s1 = __shfl(sv, j + 1);
            int s2 = __shfl(sv, j + 2), s3 = __shfl(sv, j + 3);
            float w0 = __shfl(wv, j),     w1 = __shfl(wv, j + 1);
            float w2 = __shfl(wv, j + 2), w3 = __shfl(wv, j + 3);
            unsigned int u0 = H[s0 * 64 + l];
            unsigned int u1 = H[s1 * 64 + l];
            unsigned int u2 = H[s2 * 64 + l];
            unsigned int u3 = H[s3 * 64 + l];
            a0 = fmaf(w0, bflo(u0), a0); a1 = fmaf(w0, bfhi(u0), a1);
            b0 = fmaf(w1, bflo(u1), b0); b1 = fmaf(w1, bfhi(u1), b1);
            c0 = fmaf(w2, bflo(u2), c0); c1 = fmaf(w2, bfhi(u2), c1);
            d0 = fmaf(w3, bflo(u3), d0); d1 = fmaf(w3, bfhi(u3), d1);
        }
        for (; j < m; ++j) {
            int s0 = __shfl(sv, j);
            float w0 = __shfl(wv, j);
            unsigned int u0 = H[s0 * 64 + l];
            a0 = fmaf(w0, bflo(u0), a0); a1 = fmaf(w0, bfhi(u0), a1);
        }
    }
    float o0 = fmaf(dn, (a0 + b0) + (c0 + d0), reinterpret_cast<const float2*>(bias)[l].x);
    float o1 = fmaf(dn, (a1 + b1) + (c1 + d1), reinterpret_cast<const float2*>(bias)[l].y);
    reinterpret_cast<float2*>(OUT)[n * 64 + l] = make_float2(fmaxf(o0, 0.f), fmaxf(o1, 0.f));
}

__global__ __launch_bounds__(64) void agg2_kernel(const unsigned int* __restrict__ H,   // bf16x2, ld=32
                                                  const int* __restrict__ row_start,
                                                  const unsigned short* __restrict__ csr_src,
                                                  const float* __restrict__ dinv,
                                                  const float* __restrict__ bias,
                                                  float* __restrict__ OUT) {
    int n = blockIdx.x;
    int l = threadIdx.x;
    int half = l >> 5;                  // lanes 0-31: even edges, 32-63: odd edges
    int c = l & 31;                     // channel pair {2c, 2c+1}
    float dn = dinv[n];
    unsigned int us = H[n * 32 + c];
    float a0 = half ? 0.f : dn * bflo(us);
    float a1 = half ? 0.f : dn * bfhi(us);
    float b0 = 0.f, b1 = 0.f;
    int e0 = row_start[n], e1 = row_start[n + 1];
    for (int base = e0; base < e1; base += 64) {
        int m = min(64, e1 - base);
        int sv = csr_src[base + min(l, m - 1)];
        float wv = (l < m) ? dinv[sv] : 0.f;
        int j = 0;
        for (; j + 4 <= m; j += 4) {    // per half-wave: 2 edges in flight (4 total)
            int jj0 = j + half, jj1 = j + 2 + half;
            int s0 = __shfl(sv, jj0), s1 = __shfl(sv, jj1);
            float w0 = __shfl(wv, jj0), w1 = __shfl(wv, jj1);
            unsigned int u0 = H[s0 * 32 + c];
            unsigned int u1 = H[s1 * 32 + c];
            a0 = fmaf(w0, bflo(u0), a0); a1 = fmaf(w0, bfhi(u0), a1);
            b0 = fmaf(w1, bflo(u1), b0); b1 = fmaf(w1, bfhi(u1), b1);
        }
        for (; j < m; j += 2) {
            int jj = j + half;
            int s = __shfl(sv, min(jj, m - 1));
            float w = __shfl(wv, jj);   // 0 when jj >= m (odd m, half=1)
            unsigned int u = H[s * 32 + c];
            a0 = fmaf(w, bflo(u), a0);
            a1 = fmaf(w, bfhi(u), a1);
        }
    }
    a0 += b0; a1 += b1;
    a0 += __shfl_xor(a0, 32);
    a1 += __shfl_xor(a1, 32);
    if (l < 32) {
        float2 bv = reinterpret_cast<const float2*>(bias)[c];
        float o0 = fmaf(dn, a0, bv.x);
        float o1 = fmaf(dn, a1, bv.y);
        reinterpret_cast<float2*>(OUT)[n * 32 + c] = make_float2(o0, o1);   // no ReLU
    }
}

// ---------------- launch ----------------

extern "C" void kernel_launch(void* const* d_in, const int* in_sizes, int n_in,
                              void* d_out, int out_size, void* d_ws, size_t ws_size,
                              hipStream_t stream) {
    const float* x  = (const float*)d_in[0];
    const int*   ei = (const int*)d_in[1];
    const float* W1 = (const float*)d_in[2];
    const float* b1 = (const float*)d_in[3];
    const float* W2 = (const float*)d_in[4];
    const float* b2 = (const float*)d_in[5];
    const int* srcI = ei;
    const int* dstI = ei + NE;
    float* out = (float*)d_out;

    char* ws = (char*)d_ws;
    size_t off = 0;
    auto take = [&](size_t bytes) {
        char* p = ws + off;
        off = (off + bytes + 255) & ~(size_t)255;
        return p;
    };
    int*            row_start     = (int*)take((size_t)(NN + 1) * 4);
    int*            bucket_cursor = (int*)take((size_t)NB * 4);
    int*            bucket_start  = (int*)take((size_t)(NB + 1) * 4);
    float*          dinv          = (float*)take((size_t)NN * 4);
    unsigned short* W1t_hi        = (unsigned short*)take((size_t)CH * CIN * 2);
    unsigned short* W1t_lo        = (unsigned short*)take((size_t)CH * CIN * 2);
    unsigned short* W2t_hi        = (unsigned short*)take((size_t)CO * CH * 2);
    unsigned short* W2t_lo        = (unsigned short*)take((size_t)CO * CH * 2);
    unsigned short* csr_src       = (unsigned short*)take((size_t)NE * 2);
    unsigned short* h1b           = (unsigned short*)take((size_t)NN * CH * 2);   // bf16
    float*          g1            = (float*)take((size_t)NN * CH * 4);            // fp32
    unsigned short* h2b           = (unsigned short*)take((size_t)NN * CO * 2);   // bf16
    // pairs aliases g1: pairs dead (after bucket_sort) before agg1 writes g1
    unsigned int*   pairs         = (unsigned int*)g1;   // NB*BUCKET_CAP*4 = 12.85 MB <= 25.6 MB

    wprep<<<(CIN * CH + CH * CO + 255) / 256, 256, 0, stream>>>(W1, W2, W1t_hi, W1t_lo,
                                                                W2t_hi, W2t_lo, bucket_cursor);
    fused_gemm1_scatter<<<SCAT_BLOCKS + G1_TILES, 256, 0, stream>>>(srcI, dstI, bucket_cursor,
                                                                    pairs, x, W1t_hi, W1t_lo, h1b);
    bucket_scan<<<1, 256, 0, stream>>>(bucket_cursor, bucket_start);
    bucket_sort<<<NB, 1024, 0, stream>>>(pairs, bucket_cursor, bucket_start,
                                         row_start, dinv, csr_src);

    agg1_kernel<<<NN, 64, 0, stream>>>((const unsigned int*)h1b, row_start, csr_src, dinv, b1, g1);
    gemm2_kernel<<<G2_TILES, 256, 0, stream>>>(g1, W2t_hi, W2t_lo, h2b);
    agg2_kernel<<<NN, 64, 0, stream>>>((const unsigned int*)h2b, row_start, csr_src, dinv, b2, out);
}